// Round 6
// baseline (319.120 us; speedup 1.0000x reference)
//
#include <hip/hip_runtime.h>
#include <cstdint>
#include <cstddef>

// DotProductAttention: O = softmax_q(QK^T/8 + log(mask)) @ V
// P = mask * exp(QK^T/8); L[b,k] = sum_q P; O = P @ (diag(1/L) V).
// R6 = R5 with compile fix: barrier-free, LDS-free K-loops. Each wave owns a
// 16-wide k'-slice and computes S^T (A=K, B=Q) with 16x16x32; the C-layout of
// S^T (row=quad*4+r, col=n) IS the B-fragment layout of 16x16x16 (k=quad*4+j,
// col=n), so P^T feeds the PV MFMA straight from registers. K/V/mask read
// direct from global (full-line utilization, L2-resident). Cross-wave O
// reduce once at kernel end via small LDS; k-split partials via fp32 atomics.
// Fix: 16x16x16bf16_1k intrinsic gated on __HIP_DEVICE_COMPILE__ (host pass
// doesn't declare it; host body is a dummy — function is device-only anyway).

#define LSEQ 2048
#define DHEAD 64

typedef __bf16 v8bf __attribute__((ext_vector_type(8)));
typedef __bf16 v4bf __attribute__((ext_vector_type(4)));
typedef float v4f __attribute__((ext_vector_type(4)));
typedef short v4s __attribute__((ext_vector_type(4)));

#define MFMA_QK(a, b, c) __builtin_amdgcn_mfma_f32_16x16x32_bf16(a, b, c, 0, 0, 0)

__device__ __forceinline__ v4f mfma_pv(v4bf a, v4bf b, v4f c) {
#if defined(__HIP_DEVICE_COMPILE__)
  return __builtin_amdgcn_mfma_f32_16x16x16bf16_1k(
      __builtin_bit_cast(v4s, a), __builtin_bit_cast(v4s, b), c, 0, 0, 0);
#else
  return c;  // host pass only needs this to parse
#endif
}

#if defined(__HIP_DEVICE_COMPILE__)
#define EXP2F(x) __builtin_amdgcn_exp2f(x)
#else
#define EXP2F(x) (x)
#endif

// ---- K0: cast Q,K fp32 -> bf16; Q pre-scaled by 0.125*log2(e) ---------------
__global__ __launch_bounds__(256) void cast_qk(const float* __restrict__ Q,
                                               const float* __restrict__ K,
                                               __bf16* __restrict__ Qb,
                                               __bf16* __restrict__ Kb) {
  const float S = 0.18033688011112042f;  // 0.125 * log2(e)
  size_t i = ((size_t)blockIdx.x * 256 + threadIdx.x) * 4;
  float4 q = *(const float4*)(Q + i);
  float4 k = *(const float4*)(K + i);
  v4bf qo = {(__bf16)(q.x * S), (__bf16)(q.y * S), (__bf16)(q.z * S), (__bf16)(q.w * S)};
  v4bf ko = {(__bf16)k.x, (__bf16)k.y, (__bf16)k.z, (__bf16)k.w};
  *(v4bf*)(Qb + i) = qo;
  *(v4bf*)(Kb + i) = ko;
}

// ---- K1: partial column sums Lpart[b,k][qc] = sum_{q in chunk} mask*exp ----
// Grid: b(16) x qchunk(4) x ktile(32) = 2048 WGs. Wave owns a 16-q slice;
// zero barriers in the loop, Q B-frags direct from global, K in registers.
__global__ __launch_bounds__(256) void stats_k(const __bf16* __restrict__ Qb,
                                               const __bf16* __restrict__ Kb,
                                               const float* __restrict__ mask,
                                               float* __restrict__ Lpart) {
  const int bx = blockIdx.x;
  const int b = bx >> 7;
  const int qc = (bx >> 5) & 3;
  const int k0 = (bx & 31) * 64;
  const int tid = threadIdx.x;
  const int wave = tid >> 6, lane = tid & 63;
  const int quad = lane >> 4, n = lane & 15;

  __shared__ __align__(16) float psum[4][64];

  // Persistent K A-frags: A[m=k'][d]: lane n -> K[k0+sub*16+n][dh*32+quad*8+j]
  v8bf ak[4][2];
#pragma unroll
  for (int sub = 0; sub < 4; ++sub)
#pragma unroll
    for (int dh = 0; dh < 2; ++dh)
      ak[sub][dh] = *(const v8bf*)(Kb + ((size_t)b * LSEQ + k0 + sub * 16 + n) * DHEAD +
                                   dh * 32 + quad * 8);

  float cs[4][4];
#pragma unroll
  for (int s = 0; s < 4; ++s)
#pragma unroll
    for (int r = 0; r < 4; ++r) cs[s][r] = 0.f;

  // wave's q rows: qc*512 + it*64 + wave*16 + n
  const __bf16* qbase = Qb + ((size_t)b * LSEQ + qc * 512 + wave * 16 + n) * DHEAD;
  const float* mbase = mask + (size_t)(qc * 512 + wave * 16 + n) * LSEQ + k0;

  for (int it = 0; it < 8; ++it) {
    const __bf16* qp = qbase + (size_t)it * 64 * DHEAD;
    v8bf bq0 = *(const v8bf*)(qp + quad * 8);
    v8bf bq1 = *(const v8bf*)(qp + 32 + quad * 8);
    const float* mp = mbase + (size_t)it * 64 * LSEQ;
#pragma unroll
    for (int sub = 0; sub < 4; ++sub) {
      v4f c = {0.f, 0.f, 0.f, 0.f};
      c = MFMA_QK(ak[sub][0], bq0, c);
      c = MFMA_QK(ak[sub][1], bq1, c);
      const float4 m4 = *(const float4*)(mp + sub * 16 + quad * 4);
#pragma unroll
      for (int r = 0; r < 4; ++r)
        cs[sub][r] += ((const float*)&m4)[r] * EXP2F(c[r]);
    }
  }

  // reduce over q-cols (lane n bits) then waves
#pragma unroll
  for (int sub = 0; sub < 4; ++sub) {
#pragma unroll
    for (int r = 0; r < 4; ++r) {
      float v = cs[sub][r];
      v += __shfl_xor(v, 1);
      v += __shfl_xor(v, 2);
      v += __shfl_xor(v, 4);
      v += __shfl_xor(v, 8);
      cs[sub][r] = v;
    }
    if (n == 0) {
      v4f w = {cs[sub][0], cs[sub][1], cs[sub][2], cs[sub][3]};
      *(v4f*)&psum[wave][sub * 16 + quad * 4] = w;
    }
  }
  __syncthreads();
  if (tid < 64) {
    float s = psum[0][tid] + psum[1][tid] + psum[2][tid] + psum[3][tid];
    Lpart[((size_t)b * LSEQ + k0 + tid) * 4 + qc] = s;
  }
}

// ---- K2: Vts[b][v][k] = bf16(V[b][k][v] / L[b][k]), L = sum of 4 partials --
__global__ __launch_bounds__(256) void vtrans_k(const float* __restrict__ V,
                                                const float* __restrict__ Lpart,
                                                __bf16* __restrict__ Vts) {
  const int b = blockIdx.x >> 6;
  const int k0 = (blockIdx.x & 63) * 32;
  const int tid = threadIdx.x;
  __shared__ float tile[32][65];
  __shared__ float invl[32];
  if (tid < 32) {
    float4 lp = *(const float4*)&Lpart[((size_t)b * LSEQ + k0 + tid) * 4];
    invl[tid] = 1.0f / (lp.x + lp.y + lp.z + lp.w);
  }
#pragma unroll
  for (int t = 0; t < 8; ++t) {
    int flat = t * 256 + tid;
    int k = flat >> 6, v = flat & 63;
    tile[k][v] = V[((size_t)b * LSEQ + k0 + k) * DHEAD + v];
  }
  __syncthreads();
#pragma unroll
  for (int t = 0; t < 8; ++t) {
    int flat = t * 256 + tid;
    int v = flat >> 5, k = flat & 31;
    Vts[((size_t)b * DHEAD + v) * LSEQ + k0 + k] = (__bf16)(tile[k][v] * invl[k]);
  }
}

// ---- K3: O += P_chunk @ Vts, everything in registers ------------------------
// Grid: b(16) x kc(2) x qtile32(64) = 2048 WGs. Wave owns k'-slice 16.
// XCD = bx%8 = qt%8: mask slice 2 MB per XCD (L2-resident).
__global__ __launch_bounds__(256) void attn_k(const __bf16* __restrict__ Qb,
                                              const __bf16* __restrict__ Kb,
                                              const __bf16* __restrict__ Vts,
                                              const float* __restrict__ mask,
                                              float* __restrict__ out) {
  const int bx = blockIdx.x;
  const int b = bx >> 7;
  const int kc = (bx >> 6) & 1;
  const int q0 = (bx & 63) * 32;
  const int tid = threadIdx.x;
  const int wave = tid >> 6, lane = tid & 63;
  const int quad = lane >> 4, n = lane & 15;

  __shared__ __align__(16) float Ored[32][68];  // cross-wave reduce (end only)

  // Q B-frags persistent: B[d][q]: lane n = q-col; [qt][dh]
  v8bf bq[2][2];
#pragma unroll
  for (int qt = 0; qt < 2; ++qt)
#pragma unroll
    for (int dh = 0; dh < 2; ++dh)
      bq[qt][dh] = *(const v8bf*)(Qb + ((size_t)b * LSEQ + q0 + qt * 16 + n) * DHEAD +
                                  dh * 32 + quad * 8);

  v4f acc[2][4];  // [qt][vt]: D[m=v][n=q], lane: v=vt*16+quad*4+r, q=q0+qt*16+n
#pragma unroll
  for (int qt = 0; qt < 2; ++qt)
#pragma unroll
    for (int vt = 0; vt < 4; ++vt) acc[qt][vt] = (v4f){0.f, 0.f, 0.f, 0.f};

  // wave's k' rows: kc*1024 + it*64 + wave*16 + {n | quad*4+j}
  const __bf16* kbase = Kb + ((size_t)b * LSEQ + kc * 1024 + wave * 16 + n) * DHEAD;

  for (int it = 0; it < 16; ++it) {
    // K A-frags: A[m=k'][d], m = n
    const __bf16* kp = kbase + (size_t)it * 64 * DHEAD;
    v8bf ak0 = *(const v8bf*)(kp + quad * 8);
    v8bf ak1 = *(const v8bf*)(kp + 32 + quad * 8);

    // V A-frags: A[m=v][k'], m = n, k' = kb + j
    const int kb = kc * 1024 + it * 64 + wave * 16 + quad * 4;
    v4bf av[4];
#pragma unroll
    for (int vt = 0; vt < 4; ++vt)
      av[vt] = *(const v4bf*)(Vts + ((size_t)b * DHEAD + vt * 16 + n) * LSEQ + kb);

#pragma unroll
    for (int qt = 0; qt < 2; ++qt) {
      // S^T tile: C[m=k'][n=q], lane: k' = kb + r, q = q0+qt*16+n
      v4f c = {0.f, 0.f, 0.f, 0.f};
      c = MFMA_QK(ak0, bq[qt][0], c);
      c = MFMA_QK(ak1, bq[qt][1], c);
      const float4 m4 = *(const float4*)(mask + (size_t)(q0 + qt * 16 + n) * LSEQ + kb);
      v4bf pb;  // P^T in C-layout == B-frag layout of 16x16x16 (k=quad*4+j)
#pragma unroll
      for (int r = 0; r < 4; ++r)
        pb[r] = (__bf16)(((const float*)&m4)[r] * EXP2F(c[r]));
#pragma unroll
      for (int vt = 0; vt < 4; ++vt) acc[qt][vt] = mfma_pv(av[vt], pb, acc[qt][vt]);
    }
  }

  // cross-wave reduce in LDS: Ored[q][v], serialized add rounds
#pragma unroll 1
  for (int w = 0; w < 4; ++w) {
    if (wave == w) {
#pragma unroll
      for (int qt = 0; qt < 2; ++qt)
#pragma unroll
        for (int vt = 0; vt < 4; ++vt) {
          float* p = &Ored[qt * 16 + n][vt * 16 + quad * 4];
          if (w == 0)
            *(v4f*)p = acc[qt][vt];
          else {
            v4f t = *(v4f*)p;
            t += acc[qt][vt];
            *(v4f*)p = t;
          }
        }
    }
    __syncthreads();
  }

  // cooperative atomic-add to out (zeroed; 2 kc-chunks accumulate)
  {
    const int q = tid >> 3, vb = (tid & 7) * 8;
    float* op = &out[((size_t)b * LSEQ + q0 + q) * DHEAD + vb];
#pragma unroll
    for (int i = 0; i < 8; ++i) unsafeAtomicAdd(op + i, Ored[q][vb + i]);
  }
}

extern "C" void kernel_launch(void* const* d_in, const int* in_sizes, int n_in,
                              void* d_out, int out_size, void* d_ws, size_t ws_size,
                              hipStream_t stream) {
  const float* Q = (const float*)d_in[0];
  const float* K = (const float*)d_in[1];
  const float* V = (const float*)d_in[2];
  const float* mask = (const float*)d_in[3];
  float* out = (float*)d_out;

  char* ws = (char*)d_ws;
  // ws layout: Qb 4 MiB | Kb 4 MiB | Vts 4 MiB. Lpart (512 KiB) staged in
  // d_out, consumed by vtrans_k BEFORE the memset that attn_k needs.
  __bf16* Qb = (__bf16*)(ws);
  __bf16* Kb = (__bf16*)(ws + 4194304);
  __bf16* Vts = (__bf16*)(ws + 8388608);
  float* Lpart = (float*)d_out;
  if (ws_size < 12582912) return;  // workspace too small — fail loudly

  cast_qk<<<2048, 256, 0, stream>>>(Q, K, Qb, Kb);
  stats_k<<<2048, 256, 0, stream>>>(Qb, Kb, mask, Lpart);
  vtrans_k<<<1024, 256, 0, stream>>>(V, Lpart, Vts);
  (void)hipMemsetAsync(out, 0, (size_t)out_size * sizeof(float), stream);
  attn_k<<<2048, 256, 0, stream>>>(Qb, Kb, Vts, mask, out);
}

// Round 7
// 247.296 us; speedup vs baseline: 1.2904x; 1.2904x over previous
//
#include <hip/hip_runtime.h>
#include <cstdint>
#include <cstddef>

// DotProductAttention: O = softmax_q(QK^T/8 + log(mask)) @ V
// P = mask * exp(QK^T/8); L[b,k] = sum_q P; O = P @ (diag(1/L) V).
// R7: hybrid of the two validated structures.
//  - gl_lds DMA staging of K / V^T tiles (R2/R4: batches 512x16B in flight;
//    fixes R6's serial VMEM latency chain).
//  - S^T via swapped MFMA operands; P^T stays in registers and feeds
//    mfma_f32_16x16x16bf16_1k directly (R6: C-layout == B-frag layout).
//  - float4 mask register-rotate prefetch issued between DMA and barrier.
//  - kc=1: direct coalesced stores, no atomics, no out-memset.

#define LSEQ 2048
#define DHEAD 64

typedef __bf16 v8bf __attribute__((ext_vector_type(8)));
typedef __bf16 v4bf __attribute__((ext_vector_type(4)));
typedef float v4f __attribute__((ext_vector_type(4)));
typedef short v4s __attribute__((ext_vector_type(4)));

#define MFMA_QK(a, b, c) __builtin_amdgcn_mfma_f32_16x16x32_bf16(a, b, c, 0, 0, 0)

__device__ __forceinline__ v4f mfma_pv(v4bf a, v4bf b, v4f c) {
#if defined(__HIP_DEVICE_COMPILE__)
  return __builtin_amdgcn_mfma_f32_16x16x16bf16_1k(
      __builtin_bit_cast(v4s, a), __builtin_bit_cast(v4s, b), c, 0, 0, 0);
#else
  return c;  // host pass only needs this to parse
#endif
}

#if defined(__HIP_DEVICE_COMPILE__)
#define EXP2F(x) __builtin_amdgcn_exp2f(x)
#else
#define EXP2F(x) (x)
#endif

__device__ __forceinline__ void gl_lds16(const void* g, void* l) {
  __builtin_amdgcn_global_load_lds(
      (__attribute__((address_space(1))) void*)g,
      (__attribute__((address_space(3))) void*)l, 16, 0, 0);
}

// ---- K0: cast Q,K fp32 -> bf16; Q pre-scaled by 0.125*log2(e) ---------------
__global__ __launch_bounds__(256) void cast_qk(const float* __restrict__ Q,
                                               const float* __restrict__ K,
                                               __bf16* __restrict__ Qb,
                                               __bf16* __restrict__ Kb) {
  const float S = 0.18033688011112042f;  // 0.125 * log2(e)
  size_t i = ((size_t)blockIdx.x * 256 + threadIdx.x) * 4;
  float4 q = *(const float4*)(Q + i);
  float4 k = *(const float4*)(K + i);
  v4bf qo = {(__bf16)(q.x * S), (__bf16)(q.y * S), (__bf16)(q.z * S), (__bf16)(q.w * S)};
  v4bf ko = {(__bf16)k.x, (__bf16)k.y, (__bf16)k.z, (__bf16)k.w};
  *(v4bf*)(Qb + i) = qo;
  *(v4bf*)(Kb + i) = ko;
}

// ---- K1: partial column sums Lpart[b,k][qc] = sum_{q in chunk} mask*exp ----
// Grid: b(16) x qchunk(4) x ktile(32) = 2048 WGs; XCD = kt%8 -> 2MB mask cols.
// Wave owns a 16-q slice per iter; K A-frags (all 64 k') persistent in regs;
// Q staged via gl_lds; mask float4 rotate-prefetch.
__global__ __launch_bounds__(256, 4) void stats_k(const __bf16* __restrict__ Qb,
                                                  const __bf16* __restrict__ Kb,
                                                  const float* __restrict__ mask,
                                                  float* __restrict__ Lpart) {
  const int bx = blockIdx.x;
  const int b = bx >> 7;
  const int qc = (bx >> 5) & 3;
  const int k0 = (bx & 31) * 64;
  const int tid = threadIdx.x;
  const int wave = tid >> 6, lane = tid & 63;
  const int quad = lane >> 4, n = lane & 15;

  __shared__ __align__(16) __bf16 Qt[64 * 64];
  __shared__ __align__(16) float psum[4][64];

  // Persistent K A-frags: A[m=k'][d]: lane n -> K[k0+sub*16+n][dh*32+quad*8+j]
  v8bf ak[4][2];
#pragma unroll
  for (int sub = 0; sub < 4; ++sub)
#pragma unroll
    for (int dh = 0; dh < 2; ++dh)
      ak[sub][dh] = *(const v8bf*)(Kb + ((size_t)b * LSEQ + k0 + sub * 16 + n) * DHEAD +
                                   dh * 32 + quad * 8);

  float cs[4][4];
#pragma unroll
  for (int s = 0; s < 4; ++s)
#pragma unroll
    for (int r = 0; r < 4; ++r) cs[s][r] = 0.f;

  // wave's q rows: qc*512 + it*64 + wave*16 + n
  const float* mbase = mask + (size_t)(qc * 512 + wave * 16 + n) * LSEQ + k0;
  float4 mcur[4], mnxt[4];
#pragma unroll
  for (int sub = 0; sub < 4; ++sub)
    mnxt[sub] = *(const float4*)(mbase + sub * 16 + quad * 4);

  for (int it = 0; it < 8; ++it) {
    __syncthreads();
    // stage 64 q-rows (wave w writes rows w*16..w*16+15 = its own B-frag rows)
#pragma unroll
    for (int i = 0; i < 2; ++i) {
      int s = (wave * 2 + i) * 64 + lane;
      int row = s >> 3, gc = (s & 7) ^ (row & 7);
      gl_lds16(Qb + ((size_t)b * LSEQ + qc * 512 + it * 64 + row) * DHEAD + gc * 8,
               &Qt[s * 8]);
    }
    // rotate mask; prefetch next q-iter (completes during barrier drain)
#pragma unroll
    for (int sub = 0; sub < 4; ++sub) mcur[sub] = mnxt[sub];
    const int itn = (it + 1 < 8) ? it + 1 : 0;
#pragma unroll
    for (int sub = 0; sub < 4; ++sub)
      mnxt[sub] = *(const float4*)(mbase + (size_t)itn * 64 * LSEQ + sub * 16 + quad * 4);
    __syncthreads();

    // Q B-frags for this wave's rows
    const int qr = wave * 16 + n;
    v8bf bq0 = *(const v8bf*)&Qt[qr * 64 + ((0 * 4 + quad) ^ (qr & 7)) * 8];
    v8bf bq1 = *(const v8bf*)&Qt[qr * 64 + ((1 * 4 + quad) ^ (qr & 7)) * 8];

#pragma unroll
    for (int sub = 0; sub < 4; ++sub) {
      // S^T: C[m=k'][n=q]; lane: k' = k0+sub*16+quad*4+r, q = its q-row
      v4f c = {0.f, 0.f, 0.f, 0.f};
      c = MFMA_QK(ak[sub][0], bq0, c);
      c = MFMA_QK(ak[sub][1], bq1, c);
#pragma unroll
      for (int r = 0; r < 4; ++r)
        cs[sub][r] += ((const float*)&mcur[sub])[r] * EXP2F(c[r]);
    }
  }

  // reduce over q-cols (lane n bits) then waves
#pragma unroll
  for (int sub = 0; sub < 4; ++sub) {
#pragma unroll
    for (int r = 0; r < 4; ++r) {
      float v = cs[sub][r];
      v += __shfl_xor(v, 1);
      v += __shfl_xor(v, 2);
      v += __shfl_xor(v, 4);
      v += __shfl_xor(v, 8);
      cs[sub][r] = v;
    }
    if (n == 0) {
      v4f w = {cs[sub][0], cs[sub][1], cs[sub][2], cs[sub][3]};
      *(v4f*)&psum[wave][sub * 16 + quad * 4] = w;
    }
  }
  __syncthreads();
  if (tid < 64) {
    float s = psum[0][tid] + psum[1][tid] + psum[2][tid] + psum[3][tid];
    Lpart[((size_t)b * LSEQ + k0 + tid) * 4 + qc] = s;
  }
}

// ---- K2: Vts[b][v][k] = bf16(V[b][k][v] / L[b][k]), L = sum of 4 partials --
__global__ __launch_bounds__(256) void vtrans_k(const float* __restrict__ V,
                                                const float* __restrict__ Lpart,
                                                __bf16* __restrict__ Vts) {
  const int b = blockIdx.x >> 6;
  const int k0 = (blockIdx.x & 63) * 32;
  const int tid = threadIdx.x;
  __shared__ float tile[32][65];
  __shared__ float invl[32];
  if (tid < 32) {
    float4 lp = *(const float4*)&Lpart[((size_t)b * LSEQ + k0 + tid) * 4];
    invl[tid] = 1.0f / (lp.x + lp.y + lp.z + lp.w);
  }
#pragma unroll
  for (int t = 0; t < 8; ++t) {
    int flat = t * 256 + tid;
    int k = flat >> 6, v = flat & 63;
    tile[k][v] = V[((size_t)b * LSEQ + k0 + k) * DHEAD + v];
  }
  __syncthreads();
#pragma unroll
  for (int t = 0; t < 8; ++t) {
    int flat = t * 256 + tid;
    int v = flat >> 5, k = flat & 31;
    Vts[((size_t)b * DHEAD + v) * LSEQ + k0 + k] = (__bf16)(tile[k][v] * invl[k]);
  }
}

// ---- K3: O = P @ Vts; staged K/V^T, reg P^T, direct store -------------------
// Grid: b(16) x qtile32(64) = 1024 WGs -> 4 WGs/CU; XCD = qt%8 (mask 2MB/XCD).
// Wave owns k'-slice 16 of each 64-k tile; sweeps all 32 k-tiles.
__global__ __launch_bounds__(256, 4) void attn_k(const __bf16* __restrict__ Qb,
                                                 const __bf16* __restrict__ Kb,
                                                 const __bf16* __restrict__ Vts,
                                                 const float* __restrict__ mask,
                                                 float* __restrict__ out) {
  const int bx = blockIdx.x;
  const int b = bx >> 6;
  const int q0 = (bx & 63) * 32;
  const int tid = threadIdx.x;
  const int wave = tid >> 6, lane = tid & 63;
  const int quad = lane >> 4, n = lane & 15;

  __shared__ __align__(16) __bf16 Kt[64 * 64];
  __shared__ __align__(16) __bf16 Vt[64 * 64];
  __shared__ __align__(16) float Ored[32][68];  // cross-wave reduce (end only)

  // Q B-frags persistent: B[d][q]: lane n = q-col; [qt2][dh]
  v8bf bq[2][2];
#pragma unroll
  for (int qt2 = 0; qt2 < 2; ++qt2)
#pragma unroll
    for (int dh = 0; dh < 2; ++dh)
      bq[qt2][dh] = *(const v8bf*)(Qb + ((size_t)b * LSEQ + q0 + qt2 * 16 + n) * DHEAD +
                                   dh * 32 + quad * 8);

  v4f acc[2][4];  // [qt2][vt]: D[m=v][n=q]
#pragma unroll
  for (int qt2 = 0; qt2 < 2; ++qt2)
#pragma unroll
    for (int vt = 0; vt < 4; ++vt) acc[qt2][vt] = (v4f){0.f, 0.f, 0.f, 0.f};

  // mask rows for this lane (q = q0 + qt2*16 + n); cols advance with k
  const float* mrow0 = mask + (size_t)(q0 + n) * LSEQ;
  const float* mrow1 = mask + (size_t)(q0 + 16 + n) * LSEQ;
  const int kloc = wave * 16 + quad * 4;  // wave's k' base within tile
  float4 mcur[2], mnxt[2];
  mnxt[0] = *(const float4*)(mrow0 + kloc);
  mnxt[1] = *(const float4*)(mrow1 + kloc);

  for (int it = 0; it < 32; ++it) {
    __syncthreads();
    // stage K tile (rows k', chunks d) and V^T tile (rows v, chunks k')
#pragma unroll
    for (int i = 0; i < 2; ++i) {
      int s = (wave * 2 + i) * 64 + lane;
      int row = s >> 3, gc = (s & 7) ^ (row & 7);
      gl_lds16(Kb + ((size_t)b * LSEQ + it * 64 + row) * DHEAD + gc * 8, &Kt[s * 8]);
      gl_lds16(Vts + ((size_t)b * DHEAD + row) * LSEQ + it * 64 + gc * 8, &Vt[s * 8]);
    }
    // rotate mask regs; prefetch next k-iter (completes during barrier drain)
    mcur[0] = mnxt[0];
    mcur[1] = mnxt[1];
    const int itn = (it + 1 < 32) ? it + 1 : 0;
    mnxt[0] = *(const float4*)(mrow0 + itn * 64 + kloc);
    mnxt[1] = *(const float4*)(mrow1 + itn * 64 + kloc);
    __syncthreads();

    // K A-frags for wave's k'-slice (rows wave*16+n)
    const int kr = wave * 16 + n;
    v8bf ak0 = *(const v8bf*)&Kt[kr * 64 + ((0 * 4 + quad) ^ (kr & 7)) * 8];
    v8bf ak1 = *(const v8bf*)&Kt[kr * 64 + ((1 * 4 + quad) ^ (kr & 7)) * 8];
    // V A-frags: av[vt] = Vt[vt*16+n][kloc .. kloc+3] (8B, swizzle-aware)
    v4bf av[4];
#pragma unroll
    for (int vt = 0; vt < 4; ++vt) {
      const int vr = vt * 16 + n;
      const int ch = wave * 2 + (quad >> 1);
      av[vt] = *(const v4bf*)&Vt[vr * 64 + ((ch ^ (vr & 7)) * 8) + (quad & 1) * 4];
    }

#pragma unroll
    for (int qt2 = 0; qt2 < 2; ++qt2) {
      // S^T: C[m=k'][n=q]; lane: k' = it*64+kloc+r, q = q0+qt2*16+n
      v4f c = {0.f, 0.f, 0.f, 0.f};
      c = MFMA_QK(ak0, bq[qt2][0], c);
      c = MFMA_QK(ak1, bq[qt2][1], c);
      v4bf pb;  // P^T in C-layout == B-frag layout of 16x16x16 (k=quad*4+j)
#pragma unroll
      for (int r = 0; r < 4; ++r)
        pb[r] = (__bf16)(((const float*)&mcur[qt2])[r] * EXP2F(c[r]));
#pragma unroll
      for (int vt = 0; vt < 4; ++vt) acc[qt2][vt] = mfma_pv(av[vt], pb, acc[qt2][vt]);
    }
  }

  // cross-wave reduce in LDS: Ored[q][v], serialized add rounds
#pragma unroll 1
  for (int w = 0; w < 4; ++w) {
    if (wave == w) {
#pragma unroll
      for (int qt2 = 0; qt2 < 2; ++qt2)
#pragma unroll
        for (int vt = 0; vt < 4; ++vt) {
          float* p = &Ored[qt2 * 16 + n][vt * 16 + quad * 4];
          if (w == 0)
            *(v4f*)p = acc[qt2][vt];
          else {
            v4f t = *(v4f*)p;
            t += acc[qt2][vt];
            *(v4f*)p = t;
          }
        }
    }
    __syncthreads();
  }

  // direct coalesced store (kc=1: no atomics, no memset)
  {
    const int q = tid >> 3, vb = (tid & 7) * 8;
    float* op = &out[((size_t)b * LSEQ + q0 + q) * DHEAD + vb];
    *(float4*)op = *(const float4*)&Ored[q][vb];
    *(float4*)(op + 4) = *(const float4*)&Ored[q][vb + 4];
  }
}

extern "C" void kernel_launch(void* const* d_in, const int* in_sizes, int n_in,
                              void* d_out, int out_size, void* d_ws, size_t ws_size,
                              hipStream_t stream) {
  const float* Q = (const float*)d_in[0];
  const float* K = (const float*)d_in[1];
  const float* V = (const float*)d_in[2];
  const float* mask = (const float*)d_in[3];
  float* out = (float*)d_out;

  char* ws = (char*)d_ws;
  // ws layout: Qb 4 MiB | Kb 4 MiB | Vts 4 MiB. Lpart (512 KiB) staged in
  // d_out, consumed by vtrans_k BEFORE attn_k overwrites out.
  __bf16* Qb = (__bf16*)(ws);
  __bf16* Kb = (__bf16*)(ws + 4194304);
  __bf16* Vts = (__bf16*)(ws + 8388608);
  float* Lpart = (float*)d_out;
  if (ws_size < 12582912) return;  // workspace too small — fail loudly

  cast_qk<<<2048, 256, 0, stream>>>(Q, K, Qb, Kb);
  stats_k<<<2048, 256, 0, stream>>>(Qb, Kb, mask, Lpart);
  vtrans_k<<<1024, 256, 0, stream>>>(V, Lpart, Vts);
  attn_k<<<1024, 256, 0, stream>>>(Qb, Kb, Vts, mask, out);
}